// Round 6
// baseline (124.438 us; speedup 1.0000x reference)
//
#include <hip/hip_runtime.h>
#include <stdint.h>

typedef unsigned short u16;
typedef unsigned int u32;
typedef __attribute__((ext_vector_type(8))) short bf16x8;
typedef __attribute__((ext_vector_type(4))) float f32x4;
typedef __attribute__((ext_vector_type(16))) float f32x16;

#define NTOK 1024      // H*W
#define DMODEL 256
#define NHEAD 8
#define DK 32
#define NBATCH 8
#define PER_B (DMODEL * NTOK)   // 262144

__device__ __forceinline__ float b2f(u16 h) {
    union { unsigned u; float f; } c; c.u = ((unsigned)h) << 16; return c.f;
}
__device__ __forceinline__ u16 f2b(float f) {
    unsigned u = __float_as_uint(f);
    unsigned r = u + 0x7fffu + ((u >> 16) & 1u);
    return (u16)(r >> 16);
}

// ---------------- Kernel 1: fused weight-convert + LN partial sums ----------------
__global__ void prep(const float* __restrict__ Wq, const float* __restrict__ Wk,
                     const float* __restrict__ Wv, const float* __restrict__ Wo,
                     u16* __restrict__ wb,
                     const float* __restrict__ x, float* __restrict__ part) {
    int bx = blockIdx.x;
    int t = threadIdx.x;
    if (bx < 256) {
        int m = bx >> 6;
        const float* W = (m == 0) ? Wq : (m == 1) ? Wk : (m == 2) ? Wv : Wo;
        int i = ((bx & 63) * 256 + t) * 4;
        float4 v = *(const float4*)&W[i];
        ushort4 o;
        o.x = f2b(v.x); o.y = f2b(v.y); o.z = f2b(v.z); o.w = f2b(v.w);
        *(ushort4*)&wb[m * 65536 + i] = o;
        return;
    }
    int blk = bx - 256;
    int b = blk >> 3, sl = blk & 7;
    int w = t >> 6, l = t & 63;
    const float* xb = x + (size_t)b * PER_B + sl * (PER_B / 8);
    float s = 0.f, ss = 0.f;
    for (int base = 0; base < PER_B / 8; base += 1024) {
        float4 v = *(const float4*)&xb[base + t * 4];
        s += v.x + v.y + v.z + v.w;
        ss += v.x * v.x + v.y * v.y + v.z * v.z + v.w * v.w;
    }
    for (int d = 1; d < 64; d <<= 1) {
        s += __shfl_xor(s, d, 64);
        ss += __shfl_xor(ss, d, 64);
    }
    __shared__ float red[2][4];
    if (l == 0) { red[0][w] = s; red[1][w] = ss; }
    __syncthreads();
    if (t == 0) {
        float S = red[0][0] + red[0][1] + red[0][2] + red[0][3];
        float SS = red[1][0] + red[1][1] + red[1][2] + red[1][3];
        part[(b * 8 + sl) * 2] = S;
        part[(b * 8 + sl) * 2 + 1] = SS;
    }
}

// ---------------- Kernel 2: normalize + transpose [c,n] -> [n,c], fp32 -> bf16 ----------------
__global__ void normT(const float* __restrict__ x, const float* __restrict__ part,
                      u16* __restrict__ xn) {
    int b = blockIdx.z;
    int n0 = blockIdx.x * 32;
    int c0 = blockIdx.y * 32;
    int tx = threadIdx.x, ty = threadIdx.y;   // (32, 8)
    __shared__ float s_mu, s_rs;
    __shared__ float tile[32][33];
    if (tx == 0 && ty == 0) {
        float S = 0.f, SS = 0.f;
        for (int i = 0; i < 8; ++i) { S += part[(b * 8 + i) * 2]; SS += part[(b * 8 + i) * 2 + 1]; }
        float mu = S / (float)PER_B;
        float var = SS / (float)PER_B - mu * mu;
        s_mu = mu;
        s_rs = rsqrtf(var + 1e-5f);
    }
    __syncthreads();
    float mu = s_mu, rs = s_rs;
    const float* xb = x + (size_t)b * PER_B;
#pragma unroll
    for (int i = 0; i < 4; ++i) {
        int c = c0 + ty + i * 8;
        tile[ty + i * 8][tx] = (xb[c * NTOK + n0 + tx] - mu) * rs;
    }
    __syncthreads();
    u16* xnb = xn + (size_t)b * PER_B;
#pragma unroll
    for (int i = 0; i < 4; ++i) {
        int n = n0 + ty + i * 8;
        xnb[n * DMODEL + c0 + tx] = f2b(tile[tx][ty + i * 8]);
    }
}

// ---------------- Kernel 3: fused QKV GEMM — q,k,v in ONE block per (mt,o64,b) ----------------
// grid (16 mt, 4 o64, 8 b) = 512 blocks. A-tile staged ONCE per block; per K-step:
// 4 staged tiles, 12 MFMA/wave between barriers. LDS = 40KB -> 4 blocks/CU.
// K and V stored in MFMA-fragment PANEL layouts for attn:
//   K panel: [bh][c][dh][hi][kslot32][8]  (kslot = swap23(key&31), dk = dh*16+hi*8+j)
//   V panel: [bh][c][grp][hi][dv32][8]    (key = c*32 + grp*16 + hi*8 + j)
// q-scale folds DK^-0.5 * log2(e) for attn's exp2 path.
__global__ __launch_bounds__(256, 4) void qkv_gemm(
    const u16* __restrict__ xn, const u16* __restrict__ wb,
    const float* __restrict__ bq, const float* __restrict__ bk,
    const float* __restrict__ bv,
    u16* __restrict__ qo, u16* __restrict__ ko, u16* __restrict__ vo) {
    int mt = blockIdx.x;
    int o64 = blockIdx.y;
    int b = blockIdx.z;
    int o0 = o64 * 64;

    __shared__ u16 As[2][64][40];
    __shared__ u16 Bs[2][3][64][40];
    int t = threadIdx.x;
    int w = t >> 6, l = t & 63;
    int lr = t >> 2;
    int lc = (t & 3) * 8;
    int qd = l >> 4, ln = l & 15;

    const u16* xb = xn + ((size_t)b * NTOK + mt * 64) * DMODEL;

    // prologue: stage K-tile 0 (A + 3 W panels)
    {
        *(uint4*)&As[0][lr][lc] = *(const uint4*)&xb[lr * DMODEL + lc];
#pragma unroll
        for (int sel = 0; sel < 3; ++sel)
            *(uint4*)&Bs[0][sel][lr][lc] =
                *(const uint4*)&wb[sel * 65536 + (o0 + lr) * DMODEL + lc];
    }
    __syncthreads();

    f32x4 acc[3][4] = {};
#pragma unroll
    for (int kb = 0; kb < 8; ++kb) {
        int cur = kb & 1;
        uint4 a1, b1[3];
        if (kb < 7) {
            a1 = *(const uint4*)&xb[lr * DMODEL + (kb + 1) * 32 + lc];
#pragma unroll
            for (int sel = 0; sel < 3; ++sel)
                b1[sel] = *(const uint4*)&wb[sel * 65536 + (o0 + lr) * DMODEL + (kb + 1) * 32 + lc];
        }
        bf16x8 af = *(const bf16x8*)&As[cur][w * 16 + ln][qd * 8];
#pragma unroll
        for (int sel = 0; sel < 3; ++sel) {
#pragma unroll
            for (int ns = 0; ns < 4; ++ns) {
                bf16x8 bf = *(const bf16x8*)&Bs[cur][sel][ns * 16 + ln][qd * 8];
                acc[sel][ns] = __builtin_amdgcn_mfma_f32_16x16x32_bf16(af, bf, acc[sel][ns], 0, 0, 0);
            }
        }
        if (kb < 7) {
            *(uint4*)&As[cur ^ 1][lr][lc] = a1;
#pragma unroll
            for (int sel = 0; sel < 3; ++sel)
                *(uint4*)&Bs[cur ^ 1][sel][lr][lc] = b1[sel];
            __syncthreads();
        }
    }

    // ---- epilogue: q (scaled), K panel, V panel ----
    {
        const float scale = 0.25505654344884634f;   // DK^-0.5 * log2(e)
#pragma unroll
        for (int ns = 0; ns < 4; ++ns) {
            int o = o0 + ns * 16 + ln;
            float bias_f = bq[o];
            int head = o >> 5, d = o & 31;
#pragma unroll
            for (int r = 0; r < 4; ++r) {
                int n_row = mt * 64 + w * 16 + qd * 4 + r;
                float v = (acc[0][ns][r] + bias_f) * scale;
                qo[(((size_t)b * NHEAD + head) * NTOK + n_row) * DK + d] = f2b(v);
            }
        }
    }
    {
#pragma unroll
        for (int ns = 0; ns < 4; ++ns) {
            int o = o0 + ns * 16 + ln;
            float bias_f = bk[o];
            int head = o >> 5, d = o & 31;
            int dh = d >> 4, h8 = (d >> 3) & 1, j = d & 7;
            size_t base = (size_t)(b * NHEAD + head) * 32768;
#pragma unroll
            for (int r = 0; r < 4; ++r) {
                int n_row = mt * 64 + w * 16 + qd * 4 + r;
                int c = n_row >> 5, w5 = n_row & 31;
                int kslot = (w5 & 19) | ((w5 & 4) << 1) | ((w5 & 8) >> 1);
                float v = acc[1][ns][r] + bias_f;
                ko[base + ((size_t)((c * 2 + dh) * 2 + h8)) * 256 + kslot * 8 + j] = f2b(v);
            }
        }
    }
    {
        int n0 = mt * 64 + w * 16 + qd * 4;
        int c = n0 >> 5, w5 = n0 & 31;
        int grp = (w5 >> 4) & 1, h8 = (w5 >> 3) & 1, j = w5 & 7;   // j in {0,4}
#pragma unroll
        for (int ns = 0; ns < 4; ++ns) {
            int o = o0 + ns * 16 + ln;
            float bias_f = bv[o];
            int head = o >> 5, d = o & 31;
            ushort4 pk;
            pk.x = f2b(acc[2][ns][0] + bias_f);
            pk.y = f2b(acc[2][ns][1] + bias_f);
            pk.z = f2b(acc[2][ns][2] + bias_f);
            pk.w = f2b(acc[2][ns][3] + bias_f);
            size_t base = (size_t)(b * NHEAD + head) * 32768;
            *(ushort4*)&vo[base + ((size_t)((c * 2 + grp) * 2 + h8)) * 256 + d * 8 + j] = pk;
        }
    }
}

// ---------------- Kernel 4: attention, 32x32 MFMA, in-register P, panelized K/V ----------------
// (round-4 version restored: single-stream, launch_bounds(256,4) — bisect of r5's 2-stream)
// grid (64 bh, 16 qp): bh fastest -> XCD L2 affinity. Block = 4 waves = (qsub) x (khalf).
// Wave: 32 q x 512 keys, 16 chunks of 32 keys.
//   S^T = mfma32x32x16(Kpanel, Q)x2: A-row m holds key swap23(m) (folded at store time) so
//   C reg r holds key 16*(r>>3)+8*hi+(r&7) == the PV B-fragment k-slot order. exp2 ->
//   v_perm bf16 pack -> PV mfma directly; O^T = mfma(Vpanel, P) keeps n = q = lane&31.
// Every K/V fragment load is ONE coalesced 1KB instruction at compile-time chunk offsets.
__global__ __launch_bounds__(256, 4) void attn(
    const u16* __restrict__ qws, const u16* __restrict__ kpan,
    const u16* __restrict__ vpan, u16* __restrict__ tmp) {
    int bh = blockIdx.x;
    int qp = blockIdx.y;
    int b = bh >> 3, h = bh & 7;
    const u16* Q  = qws + (size_t)bh * NTOK * DK;
    const u16* Kp = kpan + (size_t)bh * 32768;
    const u16* Vp = vpan + (size_t)bh * 32768;

    __shared__ float xl[2][64];
    __shared__ float xo[2][64][17];   // 16 + pad -> conflict-free merge

    int t = threadIdx.x;
    int w = t >> 6, l = t & 63;
    int qsub = w >> 1, khalf = w & 1;
    int l31 = l & 31, hi = l >> 5;

    int q0 = qp * 64 + qsub * 32;
    int c0 = khalf * 16;              // chunk base (512 keys per khalf)

    // Q fragments (B operand): n = q0+l31, k = hi*8+j (qf0: dk 0..15, qf1: dk 16..31)
    bf16x8 qf0 = *(const bf16x8*)&Q[(q0 + l31) * DK + hi * 8];
    bf16x8 qf1 = *(const bf16x8*)&Q[(q0 + l31) * DK + 16 + hi * 8];

    const u16* kb = Kp + (size_t)c0 * 1024 + hi * 256 + l31 * 8;
    const u16* vb = Vp + (size_t)c0 * 1024 + hi * 256 + l31 * 8;

    f32x16 oacc = {};
    float lsum = 0.f;

#pragma unroll
    for (int c = 0; c < 16; ++c) {
        bf16x8 kf0 = *(const bf16x8*)&kb[c * 1024];
        bf16x8 kf1 = *(const bf16x8*)&kb[c * 1024 + 512];
        bf16x8 va  = *(const bf16x8*)&vb[c * 1024];
        bf16x8 vg  = *(const bf16x8*)&vb[c * 1024 + 512];

        // S^T tile: 32 keys x 32 q, dk = 32 via two K=16 MFMAs
        f32x16 s = {};
        s = __builtin_amdgcn_mfma_f32_32x32x16_bf16(kf0, qf0, s, 0, 0, 0);
        s = __builtin_amdgcn_mfma_f32_32x32x16_bf16(kf1, qf1, s, 0, 0, 0);

        // p = exp2(s); reg r holds key 16*(r>>3)+8*hi+(r&7) -> regs 0..7 = pa slots,
        // regs 8..15 = pb slots, in natural order. Pack truncating bf16 via v_perm.
        union { u32 u[4]; bf16x8 v; } pa, pb;
        float ps = 0.f;
#pragma unroll
        for (int j = 0; j < 4; ++j) {
            float e0 = __builtin_amdgcn_exp2f(s[2 * j]);
            float e1 = __builtin_amdgcn_exp2f(s[2 * j + 1]);
            float e2 = __builtin_amdgcn_exp2f(s[2 * j + 8]);
            float e3 = __builtin_amdgcn_exp2f(s[2 * j + 9]);
            ps += (e0 + e1) + (e2 + e3);
            pa.u[j] = __builtin_amdgcn_perm(__float_as_uint(e1), __float_as_uint(e0), 0x07060302u);
            pb.u[j] = __builtin_amdgcn_perm(__float_as_uint(e3), __float_as_uint(e2), 0x07060302u);
        }
        lsum += ps;

        // O^T += V^T P : A = V panel frag (m=dv), B = P frag (n=q) -> col stays q = lane&31
        oacc = __builtin_amdgcn_mfma_f32_32x32x16_bf16(va, pa.v, oacc, 0, 0, 0);
        oacc = __builtin_amdgcn_mfma_f32_32x32x16_bf16(vg, pb.v, oacc, 0, 0, 0);
    }

    // merge the two k-halves (no-max softmax: plain adds)
    if (khalf == 1) {
        xl[qsub][l] = lsum;
#pragma unroll
        for (int r = 0; r < 16; ++r) xo[qsub][l][r] = oacc[r];
    }
    __syncthreads();
    if (khalf == 0) {
        lsum += xl[qsub][l];
#pragma unroll
        for (int r = 0; r < 16; ++r) oacc[r] += xo[qsub][l][r];
        // fold the two lane-halves' key partial sums (each lane's 16 regs are one q)
        lsum += __shfl_xor(lsum, 32, 64);
        float linv = 1.0f / lsum;
        int qg = q0 + l31;
        u16* op = tmp + ((size_t)b * NTOK + qg) * DMODEL + h * DK;
        // reg r -> dv = (r&3) + 8*(r>>2) + 4*hi : groups of 4 contiguous dv
#pragma unroll
        for (int g = 0; g < 4; ++g) {
            ushort4 pk;
            pk.x = f2b(oacc[g * 4 + 0] * linv);
            pk.y = f2b(oacc[g * 4 + 1] * linv);
            pk.z = f2b(oacc[g * 4 + 2] * linv);
            pk.w = f2b(oacc[g * 4 + 3] * linv);
            *(ushort4*)&op[g * 8 + hi * 4] = pk;
        }
    }
}

// ---------------- Kernel 5: output projection + bias + residual (LDS dbuf, 1 barrier/K-step) ----------------
__global__ __launch_bounds__(256, 4) void oproj(
    const u16* __restrict__ tmp, const u16* __restrict__ wb,
    const float* __restrict__ bo, const float* __restrict__ x,
    float* __restrict__ out) {
    int mt = blockIdx.x;
    int ot = blockIdx.y;
    int b = blockIdx.z;
    const u16* Wo = wb + 3 * 65536;

    __shared__ u16 As[2][64][40];
    __shared__ u16 Bs[2][64][40];
    int t = threadIdx.x;
    int w = t >> 6, l = t & 63;
    int lr = t >> 2;
    int lc = (t & 3) * 8;
    int qd = l >> 4, ln = l & 15;

    const u16* ab = tmp + ((size_t)b * NTOK + mt * 64) * DMODEL;

    {
        uint4 a0 = *(const uint4*)&ab[lr * DMODEL + lc];
        uint4 b0 = *(const uint4*)&Wo[(ot * 64 + lr) * DMODEL + lc];
        *(uint4*)&As[0][lr][lc] = a0;
        *(uint4*)&Bs[0][lr][lc] = b0;
    }
    __syncthreads();

    f32x4 acc[4] = {};
#pragma unroll
    for (int kb = 0; kb < 8; ++kb) {
        int cur = kb & 1;
        uint4 a1, b1;
        if (kb < 7) {
            a1 = *(const uint4*)&ab[lr * DMODEL + (kb + 1) * 32 + lc];
            b1 = *(const uint4*)&Wo[(ot * 64 + lr) * DMODEL + (kb + 1) * 32 + lc];
        }
        bf16x8 af = *(const bf16x8*)&As[cur][w * 16 + ln][qd * 8];
#pragma unroll
        for (int ns = 0; ns < 4; ++ns) {
            bf16x8 bf = *(const bf16x8*)&Bs[cur][ns * 16 + ln][qd * 8];
            acc[ns] = __builtin_amdgcn_mfma_f32_16x16x32_bf16(af, bf, acc[ns], 0, 0, 0);
        }
        if (kb < 7) {
            *(uint4*)&As[cur ^ 1][lr][lc] = a1;
            *(uint4*)&Bs[cur ^ 1][lr][lc] = b1;
            __syncthreads();
        }
    }
    const float* xb = x + (size_t)b * PER_B;
    float* ob = out + (size_t)b * PER_B;
#pragma unroll
    for (int ns = 0; ns < 4; ++ns) {
        int o = ot * 64 + ns * 16 + ln;
        float bias_f = bo[o];
#pragma unroll
        for (int r = 0; r < 4; ++r) {
            int n_row = mt * 64 + w * 16 + qd * 4 + r;
            size_t idx = (size_t)n_row * DMODEL + o;
            ob[idx] = acc[ns][r] + bias_f + xb[idx];
        }
    }
}

extern "C" void kernel_launch(void* const* d_in, const int* in_sizes, int n_in,
                              void* d_out, int out_size, void* d_ws, size_t ws_size,
                              hipStream_t stream) {
    const float* x  = (const float*)d_in[0];
    const float* Wq = (const float*)d_in[1];
    const float* bq = (const float*)d_in[2];
    const float* Wk = (const float*)d_in[3];
    const float* bk = (const float*)d_in[4];
    const float* Wv = (const float*)d_in[5];
    const float* bv = (const float*)d_in[6];
    const float* Wo = (const float*)d_in[7];
    const float* bo = (const float*)d_in[8];
    float* out = (float*)d_out;

    char* ws = (char*)d_ws;
    float* part = (float*)ws;                          // 1 KB
    u16* wb  = (u16*)(ws + 1024);                      // 512 KB
    u16* xn  = (u16*)(ws + 1024 + (512u << 10));       // 4 MB (reused as attn output tmp)
    u16* qws = (u16*)(ws + 1024 + (512u << 10) + (4u << 20));
    u16* kws = (u16*)(ws + 1024 + (512u << 10) + (8u << 20));   // K panel
    u16* vws = (u16*)(ws + 1024 + (512u << 10) + (12u << 20));  // V panel
    u16* tmp = xn;

    hipLaunchKernelGGL(prep, dim3(320), dim3(256), 0, stream, Wq, Wk, Wv, Wo, wb, x, part);
    hipLaunchKernelGGL(normT, dim3(32, 8, 8), dim3(32, 8), 0, stream, x, part, xn);
    hipLaunchKernelGGL(qkv_gemm, dim3(16, 4, 8), dim3(256), 0, stream,
                       xn, wb, bq, bk, bv, qws, kws, vws);
    hipLaunchKernelGGL(attn, dim3(64, 16), dim3(256), 0, stream, qws, kws, vws, tmp);
    hipLaunchKernelGGL(oproj, dim3(16, 4, 8), dim3(256), 0, stream, tmp, wb, bo, x, out);
}

// Round 7
// 112.401 us; speedup vs baseline: 1.1071x; 1.1071x over previous
//
#include <hip/hip_runtime.h>
#include <stdint.h>

typedef unsigned short u16;
typedef unsigned int u32;
typedef __attribute__((ext_vector_type(8))) short bf16x8;
typedef __attribute__((ext_vector_type(4))) float f32x4;
typedef __attribute__((ext_vector_type(16))) float f32x16;

#define NTOK 1024      // H*W
#define DMODEL 256
#define NHEAD 8
#define DK 32
#define NBATCH 8
#define PER_B (DMODEL * NTOK)   // 262144

__device__ __forceinline__ float b2f(u16 h) {
    union { unsigned u; float f; } c; c.u = ((unsigned)h) << 16; return c.f;
}
__device__ __forceinline__ u16 f2b(float f) {
    unsigned u = __float_as_uint(f);
    unsigned r = u + 0x7fffu + ((u >> 16) & 1u);
    return (u16)(r >> 16);
}

// ---------------- Kernel 1: fused weight-convert + LN partial sums ----------------
__global__ void prep(const float* __restrict__ Wq, const float* __restrict__ Wk,
                     const float* __restrict__ Wv, const float* __restrict__ Wo,
                     u16* __restrict__ wb,
                     const float* __restrict__ x, float* __restrict__ part) {
    int bx = blockIdx.x;
    int t = threadIdx.x;
    if (bx < 256) {
        int m = bx >> 6;
        const float* W = (m == 0) ? Wq : (m == 1) ? Wk : (m == 2) ? Wv : Wo;
        int i = ((bx & 63) * 256 + t) * 4;
        float4 v = *(const float4*)&W[i];
        ushort4 o;
        o.x = f2b(v.x); o.y = f2b(v.y); o.z = f2b(v.z); o.w = f2b(v.w);
        *(ushort4*)&wb[m * 65536 + i] = o;
        return;
    }
    int blk = bx - 256;
    int b = blk >> 3, sl = blk & 7;
    int w = t >> 6, l = t & 63;
    const float* xb = x + (size_t)b * PER_B + sl * (PER_B / 8);
    float s = 0.f, ss = 0.f;
    for (int base = 0; base < PER_B / 8; base += 1024) {
        float4 v = *(const float4*)&xb[base + t * 4];
        s += v.x + v.y + v.z + v.w;
        ss += v.x * v.x + v.y * v.y + v.z * v.z + v.w * v.w;
    }
    for (int d = 1; d < 64; d <<= 1) {
        s += __shfl_xor(s, d, 64);
        ss += __shfl_xor(ss, d, 64);
    }
    __shared__ float red[2][4];
    if (l == 0) { red[0][w] = s; red[1][w] = ss; }
    __syncthreads();
    if (t == 0) {
        float S = red[0][0] + red[0][1] + red[0][2] + red[0][3];
        float SS = red[1][0] + red[1][1] + red[1][2] + red[1][3];
        part[(b * 8 + sl) * 2] = S;
        part[(b * 8 + sl) * 2 + 1] = SS;
    }
}

// ---------------- Kernel 2: normalize + transpose [c,n] -> [n,c], fp32 -> bf16 ----------------
__global__ void normT(const float* __restrict__ x, const float* __restrict__ part,
                      u16* __restrict__ xn) {
    int b = blockIdx.z;
    int n0 = blockIdx.x * 32;
    int c0 = blockIdx.y * 32;
    int tx = threadIdx.x, ty = threadIdx.y;   // (32, 8)
    __shared__ float s_mu, s_rs;
    __shared__ float tile[32][33];
    if (tx == 0 && ty == 0) {
        float S = 0.f, SS = 0.f;
        for (int i = 0; i < 8; ++i) { S += part[(b * 8 + i) * 2]; SS += part[(b * 8 + i) * 2 + 1]; }
        float mu = S / (float)PER_B;
        float var = SS / (float)PER_B - mu * mu;
        s_mu = mu;
        s_rs = rsqrtf(var + 1e-5f);
    }
    __syncthreads();
    float mu = s_mu, rs = s_rs;
    const float* xb = x + (size_t)b * PER_B;
#pragma unroll
    for (int i = 0; i < 4; ++i) {
        int c = c0 + ty + i * 8;
        tile[ty + i * 8][tx] = (xb[c * NTOK + n0 + tx] - mu) * rs;
    }
    __syncthreads();
    u16* xnb = xn + (size_t)b * PER_B;
#pragma unroll
    for (int i = 0; i < 4; ++i) {
        int n = n0 + ty + i * 8;
        xnb[n * DMODEL + c0 + tx] = f2b(tile[tx][ty + i * 8]);
    }
}

// ---------------- Kernel 3: QKV projection GEMM (r4 version: non-fused, dbuf, panel K/V) ----------------
// grid (16 mt, 12 ot, 8 b) = 1536 blocks -> full TLP (the r5/r6 fused variant at 512 blocks
// = 2 blocks/CU measured +4.8us). LDS 20KB, dbuf, 1 barrier/K-step.
//   K panel: [bh][c][dh][hi][kslot32][8]  (kslot = swap23(key&31), dk = dh*16+hi*8+j)
//   V panel: [bh][c][grp][hi][dv32][8]    (key = c*32 + grp*16 + hi*8 + j)
// q-scale folds DK^-0.5 * log2(e) for attn's exp2 path.
__global__ __launch_bounds__(256, 4) void qkv_gemm(
    const u16* __restrict__ xn, const u16* __restrict__ wb,
    const float* __restrict__ bq, const float* __restrict__ bk,
    const float* __restrict__ bv,
    u16* __restrict__ qo, u16* __restrict__ ko, u16* __restrict__ vo) {
    int mt = blockIdx.x;
    int ot = blockIdx.y;
    int b = blockIdx.z;
    int sel = ot >> 2;            // 0=q 1=k 2=v
    int o0 = (ot & 3) * 64;
    const u16* W = wb + sel * 65536;

    __shared__ u16 As[2][64][40];
    __shared__ u16 Bs[2][64][40];
    int t = threadIdx.x;
    int w = t >> 6, l = t & 63;
    int lr = t >> 2;
    int lc = (t & 3) * 8;
    int qd = l >> 4, ln = l & 15;

    const u16* xb = xn + ((size_t)b * NTOK + mt * 64) * DMODEL;

    // prologue: stage K-tile 0
    {
        uint4 a0 = *(const uint4*)&xb[lr * DMODEL + lc];
        uint4 b0 = *(const uint4*)&W[(o0 + lr) * DMODEL + lc];
        *(uint4*)&As[0][lr][lc] = a0;
        *(uint4*)&Bs[0][lr][lc] = b0;
    }
    __syncthreads();

    f32x4 acc[4] = {};
#pragma unroll
    for (int kb = 0; kb < 8; ++kb) {
        int cur = kb & 1;
        uint4 a1, b1;
        if (kb < 7) {
            a1 = *(const uint4*)&xb[lr * DMODEL + (kb + 1) * 32 + lc];
            b1 = *(const uint4*)&W[(o0 + lr) * DMODEL + (kb + 1) * 32 + lc];
        }
        bf16x8 af = *(const bf16x8*)&As[cur][w * 16 + ln][qd * 8];
#pragma unroll
        for (int ns = 0; ns < 4; ++ns) {
            bf16x8 bf = *(const bf16x8*)&Bs[cur][ns * 16 + ln][qd * 8];
            acc[ns] = __builtin_amdgcn_mfma_f32_16x16x32_bf16(af, bf, acc[ns], 0, 0, 0);
        }
        if (kb < 7) {
            *(uint4*)&As[cur ^ 1][lr][lc] = a1;
            *(uint4*)&Bs[cur ^ 1][lr][lc] = b1;
            __syncthreads();
        }
    }
    if (sel == 0) {
        // q: DK^-0.5 * log2(e) so attn uses exp2 directly; layout [bh][n][DK]
        const float scale = 0.25505654344884634f;
#pragma unroll
        for (int ns = 0; ns < 4; ++ns) {
            int o = o0 + ns * 16 + ln;
            float bias_f = bq[o];
            int head = o >> 5, d = o & 31;
#pragma unroll
            for (int r = 0; r < 4; ++r) {
                int n_row = mt * 64 + w * 16 + qd * 4 + r;
                float v = (acc[ns][r] + bias_f) * scale;
                qo[(((size_t)b * NHEAD + head) * NTOK + n_row) * DK + d] = f2b(v);
            }
        }
    } else if (sel == 1) {
        // K panel: slot = swap23(key&31) folds attn's row permutation into the store
#pragma unroll
        for (int ns = 0; ns < 4; ++ns) {
            int o = o0 + ns * 16 + ln;
            float bias_f = bk[o];
            int head = o >> 5, d = o & 31;
            int dh = d >> 4, h8 = (d >> 3) & 1, j = d & 7;
            size_t base = (size_t)(b * NHEAD + head) * 32768;
#pragma unroll
            for (int r = 0; r < 4; ++r) {
                int n_row = mt * 64 + w * 16 + qd * 4 + r;
                int c = n_row >> 5, w5 = n_row & 31;
                int kslot = (w5 & 19) | ((w5 & 4) << 1) | ((w5 & 8) >> 1);
                float v = acc[ns][r] + bias_f;
                ko[base + ((size_t)((c * 2 + dh) * 2 + h8)) * 256 + kslot * 8 + j] = f2b(v);
            }
        }
    } else {
        // V panel: [c][grp][hi][dv][8keys]
        int n0 = mt * 64 + w * 16 + qd * 4;
        int c = n0 >> 5, w5 = n0 & 31;
        int grp = (w5 >> 4) & 1, h8 = (w5 >> 3) & 1, j = w5 & 7;   // j in {0,4}
#pragma unroll
        for (int ns = 0; ns < 4; ++ns) {
            int o = o0 + ns * 16 + ln;
            float bias_f = bv[o];
            int head = o >> 5, d = o & 31;
            ushort4 pk;
            pk.x = f2b(acc[ns][0] + bias_f);
            pk.y = f2b(acc[ns][1] + bias_f);
            pk.z = f2b(acc[ns][2] + bias_f);
            pk.w = f2b(acc[ns][3] + bias_f);
            size_t base = (size_t)(b * NHEAD + head) * 32768;
            *(ushort4*)&vo[base + ((size_t)((c * 2 + grp) * 2 + h8)) * 256 + d * 8 + j] = pk;
        }
    }
}

// ---------------- Kernel 4: attention (r5 version: 2-stream ILP, panelized K/V) ----------------
// grid (64 bh, 16 qp): bh fastest -> XCD L2 affinity. Block = 4 waves = (qsub) x (khalf).
// Wave: 32 q x 512 keys. TWO independent chunk streams per iteration (c and c+8): the
// load->S-mfma->exp2->pack chains are independent, sharing only the oacc MFMA accumulate
// (pipelined) -> 2x ILP on the latency-bound dependent chain. launch_bounds(256,3).
// Measured vs 1-stream (r6 bisect): -4.2us.
__global__ __launch_bounds__(256, 3) void attn(
    const u16* __restrict__ qws, const u16* __restrict__ kpan,
    const u16* __restrict__ vpan, u16* __restrict__ tmp) {
    int bh = blockIdx.x;
    int qp = blockIdx.y;
    int b = bh >> 3, h = bh & 7;
    const u16* Q  = qws + (size_t)bh * NTOK * DK;
    const u16* Kp = kpan + (size_t)bh * 32768;
    const u16* Vp = vpan + (size_t)bh * 32768;

    __shared__ float xl[2][64];
    __shared__ float xo[2][64][17];   // 16 + pad -> conflict-free merge

    int t = threadIdx.x;
    int w = t >> 6, l = t & 63;
    int qsub = w >> 1, khalf = w & 1;
    int l31 = l & 31, hi = l >> 5;

    int q0 = qp * 64 + qsub * 32;
    int c0 = khalf * 16;              // chunk base (512 keys per khalf)

    // Q fragments (B operand): n = q0+l31, k = hi*8+j (qf0: dk 0..15, qf1: dk 16..31)
    bf16x8 qf0 = *(const bf16x8*)&Q[(q0 + l31) * DK + hi * 8];
    bf16x8 qf1 = *(const bf16x8*)&Q[(q0 + l31) * DK + 16 + hi * 8];

    const u16* kb = Kp + (size_t)c0 * 1024 + hi * 256 + l31 * 8;
    const u16* vb = Vp + (size_t)c0 * 1024 + hi * 256 + l31 * 8;

    f32x16 oacc = {};
    float lsum = 0.f;

#pragma unroll
    for (int c = 0; c < 8; ++c) {
        // stream A: chunk c ; stream B: chunk c+8 (independent dep chains)
        bf16x8 kf0a = *(const bf16x8*)&kb[c * 1024];
        bf16x8 kf1a = *(const bf16x8*)&kb[c * 1024 + 512];
        bf16x8 vaa  = *(const bf16x8*)&vb[c * 1024];
        bf16x8 vga  = *(const bf16x8*)&vb[c * 1024 + 512];
        bf16x8 kf0b = *(const bf16x8*)&kb[(c + 8) * 1024];
        bf16x8 kf1b = *(const bf16x8*)&kb[(c + 8) * 1024 + 512];
        bf16x8 vab  = *(const bf16x8*)&vb[(c + 8) * 1024];
        bf16x8 vgb  = *(const bf16x8*)&vb[(c + 8) * 1024 + 512];

        f32x16 sA = {};
        sA = __builtin_amdgcn_mfma_f32_32x32x16_bf16(kf0a, qf0, sA, 0, 0, 0);
        sA = __builtin_amdgcn_mfma_f32_32x32x16_bf16(kf1a, qf1, sA, 0, 0, 0);
        f32x16 sB = {};
        sB = __builtin_amdgcn_mfma_f32_32x32x16_bf16(kf0b, qf0, sB, 0, 0, 0);
        sB = __builtin_amdgcn_mfma_f32_32x32x16_bf16(kf1b, qf1, sB, 0, 0, 0);

        union { u32 u[4]; bf16x8 v; } paa, pba, pab, pbb;
        float psA = 0.f, psB = 0.f;
#pragma unroll
        for (int j = 0; j < 4; ++j) {
            float a0 = __builtin_amdgcn_exp2f(sA[2 * j]);
            float a1 = __builtin_amdgcn_exp2f(sA[2 * j + 1]);
            float a2 = __builtin_amdgcn_exp2f(sA[2 * j + 8]);
            float a3 = __builtin_amdgcn_exp2f(sA[2 * j + 9]);
            psA += (a0 + a1) + (a2 + a3);
            paa.u[j] = __builtin_amdgcn_perm(__float_as_uint(a1), __float_as_uint(a0), 0x07060302u);
            pba.u[j] = __builtin_amdgcn_perm(__float_as_uint(a3), __float_as_uint(a2), 0x07060302u);
            float b0 = __builtin_amdgcn_exp2f(sB[2 * j]);
            float b1 = __builtin_amdgcn_exp2f(sB[2 * j + 1]);
            float b2 = __builtin_amdgcn_exp2f(sB[2 * j + 8]);
            float b3 = __builtin_amdgcn_exp2f(sB[2 * j + 9]);
            psB += (b0 + b1) + (b2 + b3);
            pab.u[j] = __builtin_amdgcn_perm(__float_as_uint(b1), __float_as_uint(b0), 0x07060302u);
            pbb.u[j] = __builtin_amdgcn_perm(__float_as_uint(b3), __float_as_uint(b2), 0x07060302u);
        }
        lsum += psA + psB;

        // O^T += V^T P for both streams (shared accumulator, pipelined MFMA chain)
        oacc = __builtin_amdgcn_mfma_f32_32x32x16_bf16(vaa, paa.v, oacc, 0, 0, 0);
        oacc = __builtin_amdgcn_mfma_f32_32x32x16_bf16(vga, pba.v, oacc, 0, 0, 0);
        oacc = __builtin_amdgcn_mfma_f32_32x32x16_bf16(vab, pab.v, oacc, 0, 0, 0);
        oacc = __builtin_amdgcn_mfma_f32_32x32x16_bf16(vgb, pbb.v, oacc, 0, 0, 0);
    }

    // merge the two k-halves (no-max softmax: plain adds)
    if (khalf == 1) {
        xl[qsub][l] = lsum;
#pragma unroll
        for (int r = 0; r < 16; ++r) xo[qsub][l][r] = oacc[r];
    }
    __syncthreads();
    if (khalf == 0) {
        lsum += xl[qsub][l];
#pragma unroll
        for (int r = 0; r < 16; ++r) oacc[r] += xo[qsub][l][r];
        // fold the two lane-halves' key partial sums (each lane's 16 regs are one q)
        lsum += __shfl_xor(lsum, 32, 64);
        float linv = 1.0f / lsum;
        int qg = q0 + l31;
        u16* op = tmp + ((size_t)b * NTOK + qg) * DMODEL + h * DK;
        // reg r -> dv = (r&3) + 8*(r>>2) + 4*hi : groups of 4 contiguous dv
#pragma unroll
        for (int g = 0; g < 4; ++g) {
            ushort4 pk;
            pk.x = f2b(oacc[g * 4 + 0] * linv);
            pk.y = f2b(oacc[g * 4 + 1] * linv);
            pk.z = f2b(oacc[g * 4 + 2] * linv);
            pk.w = f2b(oacc[g * 4 + 3] * linv);
            *(ushort4*)&op[g * 8 + hi * 4] = pk;
        }
    }
}

// ---------------- Kernel 5: output projection + bias + residual (LDS dbuf, 1 barrier/K-step) ----------------
__global__ __launch_bounds__(256, 4) void oproj(
    const u16* __restrict__ tmp, const u16* __restrict__ wb,
    const float* __restrict__ bo, const float* __restrict__ x,
    float* __restrict__ out) {
    int mt = blockIdx.x;
    int ot = blockIdx.y;
    int b = blockIdx.z;
    const u16* Wo = wb + 3 * 65536;

    __shared__ u16 As[2][64][40];
    __shared__ u16 Bs[2][64][40];
    int t = threadIdx.x;
    int w = t >> 6, l = t & 63;
    int lr = t >> 2;
    int lc = (t & 3) * 8;
    int qd = l >> 4, ln = l & 15;

    const u16* ab = tmp + ((size_t)b * NTOK + mt * 64) * DMODEL;

    {
        uint4 a0 = *(const uint4*)&ab[lr * DMODEL + lc];
        uint4 b0 = *(const uint4*)&Wo[(ot * 64 + lr) * DMODEL + lc];
        *(uint4*)&As[0][lr][lc] = a0;
        *(uint4*)&Bs[0][lr][lc] = b0;
    }
    __syncthreads();

    f32x4 acc[4] = {};
#pragma unroll
    for (int kb = 0; kb < 8; ++kb) {
        int cur = kb & 1;
        uint4 a1, b1;
        if (kb < 7) {
            a1 = *(const uint4*)&ab[lr * DMODEL + (kb + 1) * 32 + lc];
            b1 = *(const uint4*)&Wo[(ot * 64 + lr) * DMODEL + (kb + 1) * 32 + lc];
        }
        bf16x8 af = *(const bf16x8*)&As[cur][w * 16 + ln][qd * 8];
#pragma unroll
        for (int ns = 0; ns < 4; ++ns) {
            bf16x8 bf = *(const bf16x8*)&Bs[cur][ns * 16 + ln][qd * 8];
            acc[ns] = __builtin_amdgcn_mfma_f32_16x16x32_bf16(af, bf, acc[ns], 0, 0, 0);
        }
        if (kb < 7) {
            *(uint4*)&As[cur ^ 1][lr][lc] = a1;
            *(uint4*)&Bs[cur ^ 1][lr][lc] = b1;
            __syncthreads();
        }
    }
    const float* xb = x + (size_t)b * PER_B;
    float* ob = out + (size_t)b * PER_B;
#pragma unroll
    for (int ns = 0; ns < 4; ++ns) {
        int o = ot * 64 + ns * 16 + ln;
        float bias_f = bo[o];
#pragma unroll
        for (int r = 0; r < 4; ++r) {
            int n_row = mt * 64 + w * 16 + qd * 4 + r;
            size_t idx = (size_t)n_row * DMODEL + o;
            ob[idx] = acc[ns][r] + bias_f + xb[idx];
        }
    }
}

extern "C" void kernel_launch(void* const* d_in, const int* in_sizes, int n_in,
                              void* d_out, int out_size, void* d_ws, size_t ws_size,
                              hipStream_t stream) {
    const float* x  = (const float*)d_in[0];
    const float* Wq = (const float*)d_in[1];
    const float* bq = (const float*)d_in[2];
    const float* Wk = (const float*)d_in[3];
    const float* bk = (const float*)d_in[4];
    const float* Wv = (const float*)d_in[5];
    const float* bv = (const float*)d_in[6];
    const float* Wo = (const float*)d_in[7];
    const float* bo = (const float*)d_in[8];
    float* out = (float*)d_out;

    char* ws = (char*)d_ws;
    float* part = (float*)ws;                          // 1 KB
    u16* wb  = (u16*)(ws + 1024);                      // 512 KB
    u16* xn  = (u16*)(ws + 1024 + (512u << 10));       // 4 MB (reused as attn output tmp)
    u16* qws = (u16*)(ws + 1024 + (512u << 10) + (4u << 20));
    u16* kws = (u16*)(ws + 1024 + (512u << 10) + (8u << 20));   // K panel
    u16* vws = (u16*)(ws + 1024 + (512u << 10) + (12u << 20));  // V panel
    u16* tmp = xn;

    hipLaunchKernelGGL(prep, dim3(320), dim3(256), 0, stream, Wq, Wk, Wv, Wo, wb, x, part);
    hipLaunchKernelGGL(normT, dim3(32, 8, 8), dim3(32, 8), 0, stream, x, part, xn);
    hipLaunchKernelGGL(qkv_gemm, dim3(16, 12, 8), dim3(256), 0, stream,
                       xn, wb, bq, bk, bv, qws, kws, vws);
    hipLaunchKernelGGL(attn, dim3(64, 16), dim3(256), 0, stream, qws, kws, vws, tmp);
    hipLaunchKernelGGL(oproj, dim3(16, 4, 8), dim3(256), 0, stream, tmp, wb, bo, x, out);
}